// Round 2
// baseline (2880.011 us; speedup 1.0000x reference)
//
#include <hip/hip_runtime.h>

// SSMTrack: B=8, S=4096, H=1024, D=256
//   inp = x @ W_in + b_in                    (bf16 MFMA GEMM)
//   s_t = tanh(inp_t + s_{t-1} @ W_state + b_state)   (MFMA f16 scan, 1 WG/batch)
//   out = states @ W_out + b_out             (bf16 MFMA GEMM)

typedef float v4f __attribute__((ext_vector_type(4)));
typedef __bf16 bf16x4 __attribute__((ext_vector_type(4)));
typedef __bf16 bf16x8 __attribute__((ext_vector_type(8)));
typedef _Float16 h8 __attribute__((ext_vector_type(8)));

#define BARRIER_LGKM() asm volatile("s_waitcnt lgkmcnt(0)\n\ts_barrier" ::: "memory")

// ---------------------------------------------------------------- conversions
__global__ void cvt_f32_bf16_x4(const float* __restrict__ in,
                                __bf16* __restrict__ out, int n4) {
  int i = blockIdx.x * blockDim.x + threadIdx.x;
  if (i >= n4) return;
  v4f v = ((const v4f*)in)[i];
  bf16x4 o;
  o.x = (__bf16)v.x; o.y = (__bf16)v.y; o.z = (__bf16)v.z; o.w = (__bf16)v.w;
  ((bf16x4*)out)[i] = o;
}

// in: [K,N] f32 row-major  ->  out: [N,K] bf16 row-major (i.e. B^T)
__global__ void transpose_cvt(const float* __restrict__ in,
                              __bf16* __restrict__ out, int K, int N) {
  int i = blockIdx.x * blockDim.x + threadIdx.x;
  if (i >= K * N) return;
  int k = i / N;
  int n = i - k * N;
  out[(size_t)n * K + k] = (__bf16)in[i];
}

// ---------------------------------------------------------------- GEMM (bf16)
// C[M,N] (f32) = A[M,K](bf16, row-major) * B  where Bt[N,K] = B^T (bf16)
// One wave per 16x16 C-tile, fragments loaded straight from global.
// C/D: col = l&15, row = (l>>4)*4 + i   (m89-verified)
__global__ void gemm_bt(const __bf16* __restrict__ A,
                        const __bf16* __restrict__ Bt,
                        const float* __restrict__ bias,
                        float* __restrict__ C,
                        int M, int N, int K) {
  int wid  = (blockIdx.x * blockDim.x + threadIdx.x) >> 6;
  int lane = threadIdx.x & 63;
  int ntiles = N >> 4;
  int mt = wid / ntiles;          // nt inner so consecutive waves share A rows
  int nt = wid - mt * ntiles;
  if (mt * 16 >= M) return;
  int r = lane & 15;
  int q = lane >> 4;
  const __bf16* arow = A + (size_t)(mt * 16 + r) * K + q * 8;
  const __bf16* brow = Bt + (size_t)(nt * 16 + r) * K + q * 8;
  v4f acc = {0.f, 0.f, 0.f, 0.f};
  for (int k = 0; k < K; k += 32) {
    bf16x8 af = *(const bf16x8*)(arow + k);
    bf16x8 bf = *(const bf16x8*)(brow + k);
    acc = __builtin_amdgcn_mfma_f32_16x16x32_bf16(af, bf, acc, 0, 0, 0);
  }
  int col = nt * 16 + r;
  float bv = bias[col];
  size_t base = (size_t)(mt * 16 + q * 4) * N + col;
#pragma unroll
  for (int i = 0; i < 4; ++i) C[base + (size_t)i * N] = acc[i] + bv;
}

// ---------------------------------------------------------------- scan (MFMA)
// One block (256 threads = 4 waves) per batch. Each step is
//   s_t[256] = tanh(inp_t + s_{t-1} @ W_state + b_state)
// done as MFMA 16x16x32_f16 with ALL 16 A-rows aliased to the state vector
// (A-fragment LDS address depends only on lane>>4 -> 4-address broadcast,
// conflict-free). Wave w owns output n-tiles {4w..4w+3} (cols w*64..w*64+63)
// and holds W_state for those columns permanently in registers (AGPR-
// eligible) as f16 B-fragments.
//
// R1 change: split-K. MfmaUtil showed ~45% pipe occupancy on the active CUs
// (~16 cy/MFMA effective) -> dependent-accumulate latency (~64 cy) with only
// 4 independent chains was the bottleneck. Now each tile's K=256 is split
// into 4 accumulators (chunks {2s,2s+1}) -> 16 independent chains of depth
// 2; issue order does all 16 depth-0 MFMAs (80 cy) before any depth-1, so
// the pipe never stalls on an accumulator. 3 extra scalar adds per lane at
// extraction.
__global__ __launch_bounds__(256, 1) void scan_mfma(
    const float* __restrict__ inp,      // [B*S, 256] f32
    const float* __restrict__ Wst,      // [256, 256] f32
    const float* __restrict__ b_state,  // [256] f32
    __bf16* __restrict__ states,        // [B*S, 256] bf16 (out)
    int S) {
  const int tid = threadIdx.x;        // == output column this lane writes
  const int l = tid & 63;
  const int q = l >> 4;
  const int r = l & 15;
  const int w = tid >> 6;             // wave 0..3
  const int b = blockIdx.x;

  __shared__ __align__(16) _Float16 sbuf[2][256];

  // B-fragments for mfma_f32_16x16x32_f16: lane holds B[k][col] with
  // col = 16*tile + r, k = 32*c + 8*q + i. One-time f32->f16 convert.
  h8 bw0[8], bw1[8], bw2[8], bw3[8];
#pragma unroll
  for (int c = 0; c < 8; ++c) {
#pragma unroll
    for (int i = 0; i < 8; ++i) {
      const float* wr = Wst + (size_t)(32 * c + 8 * q + i) * 256 + w * 64 + r;
      bw0[c][i] = (_Float16)wr[0];
      bw1[c][i] = (_Float16)wr[16];
      bw2[c][i] = (_Float16)wr[32];
      bw3[c][i] = (_Float16)wr[48];
    }
  }

  const float bst = b_state[tid];
  const float* inpb = inp + (size_t)b * S * 256;
  __bf16* stb = states + (size_t)b * S * 256;

  sbuf[0][tid] = (_Float16)0.f;  // state0 = 0
  float u_cur = inpb[tid];                 // u for t=0
  float u_nxt = inpb[256 + tid];           // u for t=1 (S >= 2)
  __syncthreads();

  int cur = 0;
  for (int t = 0; t < S; ++t) {
    // prefetch u for t+2 so ~500cy of global latency hides under 2 steps
    float u_n2 = 0.f;
    if (t + 2 < S) u_n2 = inpb[(size_t)(t + 2) * 256 + tid];

    // A-fragments: address = 64*c + 16*q bytes -> 4 distinct addresses,
    // broadcast over 16-lane groups; all 16 A-rows = state.
    const h8* sp = (const h8*)sbuf[cur];
    h8 af[8];
#pragma unroll
    for (int c = 0; c < 8; ++c) af[c] = sp[4 * c + q];

    // acc[tile][split]: split s covers k-chunks {2s, 2s+1}
    v4f acc[4][4];
#pragma unroll
    for (int tI = 0; tI < 4; ++tI)
#pragma unroll
      for (int s = 0; s < 4; ++s) acc[tI][s] = (v4f){0.f, 0.f, 0.f, 0.f};

#pragma unroll
    for (int d = 0; d < 2; ++d) {
#pragma unroll
      for (int s = 0; s < 4; ++s) {
        const int c = 2 * s + d;
        acc[0][s] = __builtin_amdgcn_mfma_f32_16x16x32_f16(af[c], bw0[c], acc[0][s], 0, 0, 0);
        acc[1][s] = __builtin_amdgcn_mfma_f32_16x16x32_f16(af[c], bw1[c], acc[1][s], 0, 0, 0);
        acc[2][s] = __builtin_amdgcn_mfma_f32_16x16x32_f16(af[c], bw2[c], acc[2][s], 0, 0, 0);
        acc[3][s] = __builtin_amdgcn_mfma_f32_16x16x32_f16(af[c], bw3[c], acc[3][s], 0, 0, 0);
      }
    }

    // lane writes col = w*64 + l = 16*(4w+q) + r -> n-tile index q, row 4q -> acc elem 0
    float xq0 = (acc[0][0][0] + acc[0][1][0]) + (acc[0][2][0] + acc[0][3][0]);
    float xq1 = (acc[1][0][0] + acc[1][1][0]) + (acc[1][2][0] + acc[1][3][0]);
    float xq2 = (acc[2][0][0] + acc[2][1][0]) + (acc[2][2][0] + acc[2][3][0]);
    float xq3 = (acc[3][0][0] + acc[3][1][0]) + (acc[3][2][0] + acc[3][3][0]);
    float x = (q == 0) ? xq0 : (q == 1) ? xq1 : (q == 2) ? xq2 : xq3;
    x += u_cur + bst;

    // tanh(x) = 1 - 2/(exp2(2*log2e*x)+1)
    float e = exp2f(2.885390082f * x);
    float sn = 1.f - 2.f * __builtin_amdgcn_rcpf(e + 1.f);

    cur ^= 1;
    sbuf[cur][tid] = (_Float16)sn;            // ds_write_b16
    stb[(size_t)t * 256 + tid] = (__bf16)sn;  // fire-and-forget global store
    u_cur = u_nxt;
    u_nxt = u_n2;
    BARRIER_LGKM();
  }
}

// ---------------------------------------------------------------- launch
extern "C" void kernel_launch(void* const* d_in, const int* in_sizes, int n_in,
                              void* d_out, int out_size, void* d_ws,
                              size_t ws_size, hipStream_t stream) {
  const float* x       = (const float*)d_in[0];  // [8,4096,1024]
  const float* W_in    = (const float*)d_in[1];  // [1024,256]
  const float* b_in    = (const float*)d_in[2];  // [256]
  const float* W_state = (const float*)d_in[3];  // [256,256]
  const float* b_state = (const float*)d_in[4];  // [256]
  const float* W_out   = (const float*)d_in[5];  // [256,1024]
  const float* b_out   = (const float*)d_in[6];  // [1024]
  float* out = (float*)d_out;                    // [8,4096,1024]

  const int B = 8, S = 4096, H = 1024, D = 256;
  const int M = B * S;  // 32768

  char* ws = (char*)d_ws;
  float*  inp    = (float*)(ws + 0);            // 32 MB  [M,D] f32
  __bf16* states = (__bf16*)(ws + 33554432);    // 16 MB  [M,D] bf16
  __bf16* xb     = (__bf16*)(ws + 50331648);    // 64 MB  [M,H] bf16
  __bf16* WinT   = (__bf16*)(ws + 117440512);   // 0.5 MB [D,H] bf16  (W_in^T)
  __bf16* WoutT  = (__bf16*)(ws + 117964800);   // 0.5 MB [H,D] bf16  (W_out^T)

  // conversions
  cvt_f32_bf16_x4<<<(M * H / 4 + 255) / 256, 256, 0, stream>>>(x, xb, M * H / 4);
  transpose_cvt<<<(H * D + 255) / 256, 256, 0, stream>>>(W_in, WinT, H, D);
  transpose_cvt<<<(D * H + 255) / 256, 256, 0, stream>>>(W_out, WoutT, D, H);

  // phase 1: inp = x @ W_in + b_in   (M=32768, N=256, K=1024)
  {
    int waves = (M / 16) * (D / 16);
    gemm_bt<<<waves / 4, 256, 0, stream>>>(xb, WinT, b_in, inp, M, D, H);
  }

  // phase 2: sequential scan, one block (4 waves) per batch
  scan_mfma<<<B, 256, 0, stream>>>(inp, W_state, b_state, states, S);

  // phase 3: out = states @ W_out + b_out   (M=32768, N=1024, K=256)
  {
    int waves = (M / 16) * (H / 16);
    gemm_bt<<<waves / 4, 256, 0, stream>>>(states, WoutT, b_out, out, M, H, D);
  }
}

// Round 3
// 2454.352 us; speedup vs baseline: 1.1734x; 1.1734x over previous
//
#include <hip/hip_runtime.h>
#include <stdint.h>

// SSMTrack: B=8, S=4096, H=1024, D=256
//   inp = x @ W_in + b_in                    (tiled bf16 MFMA GEMM)
//   s_t = tanh(inp_t + s_{t-1} @ W_state + b_state)   (MFMA f16 scan, 1 WG/batch)
//   out = states @ W_out + b_out             (tiled bf16 MFMA GEMM)

typedef float v4f __attribute__((ext_vector_type(4)));
typedef __bf16 bf16x4 __attribute__((ext_vector_type(4)));
typedef __bf16 bf16x8 __attribute__((ext_vector_type(8)));
typedef _Float16 h8 __attribute__((ext_vector_type(8)));

#define BARRIER_LGKM() asm volatile("s_waitcnt lgkmcnt(0)\n\ts_barrier" ::: "memory")

#define GLOAD_LDS16(g, l)                                                    \
  __builtin_amdgcn_global_load_lds(                                          \
      (const __attribute__((address_space(1))) void*)(g),                    \
      (__attribute__((address_space(3))) void*)(l), 16, 0, 0)

// ---------------------------------------------------------------- conversions
__global__ void cvt_f32_bf16_x4(const float* __restrict__ in,
                                __bf16* __restrict__ out, int n4) {
  int i = blockIdx.x * blockDim.x + threadIdx.x;
  if (i >= n4) return;
  v4f v = ((const v4f*)in)[i];
  bf16x4 o;
  o.x = (__bf16)v.x; o.y = (__bf16)v.y; o.z = (__bf16)v.z; o.w = (__bf16)v.w;
  ((bf16x4*)out)[i] = o;
}

// in: [K,N] f32 row-major  ->  out: [N,K] bf16 row-major (i.e. B^T)
__global__ void transpose_cvt(const float* __restrict__ in,
                              __bf16* __restrict__ out, int K, int N) {
  int i = blockIdx.x * blockDim.x + threadIdx.x;
  if (i >= K * N) return;
  int k = i / N;
  int n = i - k * N;
  out[(size_t)n * K + k] = (__bf16)in[i];
}

// ---------------------------------------------------------------- GEMM (bf16)
// C[M,N](f32) = A[M,K](bf16 rm) * B + bias, with Bt[N,K] = B^T (bf16 rm).
// m97-style: 128x128 block tile, BK=32, 256 threads = 4 waves (2x2), each
// wave a 64x64 sub-tile = 4x4 fragments of 16x16x32 MFMA. Double-buffered
// LDS staged via global_load_lds (16B), one barrier per K-step.
// LDS swizzle: 16B-slot s of row -> s ^ ((row>>1)&3). Write side is linear
// (wave-uniform base + lane*16), so the swizzle is applied by pre-swizzling
// the per-lane GLOBAL source slot (m173 pattern); ds_read applies the same
// XOR. 16 lanes of a frag-read then cover all 8 16B-positions of the 128B
// bank row twice -> 2-way = conflict-free (m136).
__global__ __launch_bounds__(256) void gemm_tile(
    const __bf16* __restrict__ A,    // [M,K]
    const __bf16* __restrict__ Bt,   // [N,K]
    const float* __restrict__ bias,  // [N]
    float* __restrict__ C,           // [M,N]
    int M, int N, int K) {
  const int tid = threadIdx.x;
  const int lane = tid & 63;
  const int w = tid >> 6;          // wave 0..3
  const int wr = w >> 1, wc = w & 1;
  const int r = lane & 15, q = lane >> 4;

  const int nbn = N >> 7;
  const int mb = blockIdx.x / nbn;
  const int nb = blockIdx.x - mb * nbn;
  const int m0 = mb << 7, n0 = nb << 7;

  __shared__ __align__(16) char lds[2][16384];  // [buf][A 8K | B 8K]

  // staging: thread covers 2 chunks of A-tile and 2 of B-tile (16B each).
  // linear LDS offset o = (w*2+j)*1024 + lane*16 -> (row = o>>6, slot = (o>>4)&3)
  const __bf16* gA[2];
  const __bf16* gB[2];
  int loff[2];
#pragma unroll
  for (int j = 0; j < 2; ++j) {
    int o = (w * 2 + j) * 1024 + lane * 16;
    int row = o >> 6;
    int s = (o >> 4) & 3;
    int ss = s ^ ((row >> 1) & 3);  // source slot (inverse swizzle = same XOR)
    gA[j] = A + (size_t)(m0 + row) * K + ss * 8;
    gB[j] = Bt + (size_t)(n0 + row) * K + ss * 8;
    loff[j] = (w * 2 + j) * 1024;   // wave-uniform
  }

  // ds_read byte offsets (fixed per lane; +8192 for B half)
  const int slot = (q ^ ((r >> 1) & 3)) * 16;
  int aoff[4], boff[4];
#pragma unroll
  for (int i = 0; i < 4; ++i) {
    aoff[i] = (wr * 64 + i * 16 + r) * 64 + slot;
    boff[i] = 8192 + (wc * 64 + i * 16 + r) * 64 + slot;
  }

  v4f acc[4][4];
#pragma unroll
  for (int mi = 0; mi < 4; ++mi)
#pragma unroll
    for (int ni = 0; ni < 4; ++ni) acc[mi][ni] = (v4f){0.f, 0.f, 0.f, 0.f};

  const int NK = K >> 5;
  // prologue stage of buf0 (kt=0)
#pragma unroll
  for (int j = 0; j < 2; ++j) {
    GLOAD_LDS16(gA[j], lds[0] + loff[j]);
    GLOAD_LDS16(gB[j], lds[0] + 8192 + loff[j]);
  }

  for (int kt = 0; kt < NK; ++kt) {
    __syncthreads();  // drains vmcnt+lgkm: buf[kt&1] staged, old reads done
    if (kt + 1 < NK) {
      const int b = (kt + 1) & 1;
      const int ke = (kt + 1) * 32;
#pragma unroll
      for (int j = 0; j < 2; ++j) {
        GLOAD_LDS16(gA[j] + ke, lds[b] + loff[j]);
        GLOAD_LDS16(gB[j] + ke, lds[b] + 8192 + loff[j]);
      }
    }
    const char* Lb = lds[kt & 1];
    bf16x8 af[4], bf[4];
#pragma unroll
    for (int i = 0; i < 4; ++i) af[i] = *(const bf16x8*)(Lb + aoff[i]);
#pragma unroll
    for (int i = 0; i < 4; ++i) bf[i] = *(const bf16x8*)(Lb + boff[i]);
#pragma unroll
    for (int mi = 0; mi < 4; ++mi)
#pragma unroll
      for (int ni = 0; ni < 4; ++ni)
        acc[mi][ni] = __builtin_amdgcn_mfma_f32_16x16x32_bf16(
            af[mi], bf[ni], acc[mi][ni], 0, 0, 0);
  }

  // epilogue: C/D frag layout col = l&15, row = 4q+i (m89-verified)
  float bv[4];
#pragma unroll
  for (int ni = 0; ni < 4; ++ni) bv[ni] = bias[n0 + wc * 64 + ni * 16 + r];
#pragma unroll
  for (int mi = 0; mi < 4; ++mi) {
    int rowb = m0 + wr * 64 + mi * 16 + q * 4;
#pragma unroll
    for (int ni = 0; ni < 4; ++ni) {
      int col = n0 + wc * 64 + ni * 16 + r;
      float* cp = C + (size_t)rowb * N + col;
#pragma unroll
      for (int i = 0; i < 4; ++i) cp[(size_t)i * N] = acc[mi][ni][i] + bv[ni];
    }
  }
}

// ---------------------------------------------------------------- scan (MFMA)
// One block (256 threads = 4 waves) per batch. MFMA 16x16x32_f16 with all 16
// A-rows aliased to the state vector (4-address LDS broadcast). Wave w owns
// cols w*64..w*64+63 (4 n-tiles), W_state held in registers as B-fragments.
// R2: reverted to depth-8 chains (R1 split-K kept MFMA pipe busy identical
// ~506 cy/step but doubled VALU -> net regression; step time = sum of pipe
// occupancies, MFMA pipe is throughput-bound at ~16cy/MFMA/SIMD). Per-iter
// address math replaced by pointer increments; u-prefetch unconditional
// (reads <=2 rows past the slab land in the allocated states region, unused).
__global__ __launch_bounds__(256, 1) void scan_mfma(
    const float* __restrict__ inp,      // [B*S, 256] f32
    const float* __restrict__ Wst,      // [256, 256] f32
    const float* __restrict__ b_state,  // [256] f32
    __bf16* __restrict__ states,        // [B*S, 256] bf16 (out)
    int S) {
  const int tid = threadIdx.x;        // == output column this lane writes
  const int l = tid & 63;
  const int q = l >> 4;
  const int r = l & 15;
  const int w = tid >> 6;             // wave 0..3
  const int b = blockIdx.x;

  __shared__ __align__(16) _Float16 sbuf[2][256];

  // B-fragments: lane holds B[k][col], col = 16*tile + r, k = 32*c + 8*q + i.
  h8 bw0[8], bw1[8], bw2[8], bw3[8];
#pragma unroll
  for (int c = 0; c < 8; ++c) {
#pragma unroll
    for (int i = 0; i < 8; ++i) {
      const float* wr_ = Wst + (size_t)(32 * c + 8 * q + i) * 256 + w * 64 + r;
      bw0[c][i] = (_Float16)wr_[0];
      bw1[c][i] = (_Float16)wr_[16];
      bw2[c][i] = (_Float16)wr_[32];
      bw3[c][i] = (_Float16)wr_[48];
    }
  }

  const float bst = b_state[tid];
  const float* inpb = inp + (size_t)b * S * 256;
  __bf16* stb = states + (size_t)b * S * 256;

  sbuf[0][tid] = (_Float16)0.f;       // state0 = 0
  float u_cur = inpb[tid];            // u for t=0
  float u_nxt = inpb[256 + tid];      // u for t=1
  const float* pin = inpb + 512;      // -> u for t=2
  __bf16* pst = stb;
  __syncthreads();

  int cur = 0;
  for (int t = 0; t < S; ++t) {
    float u_n2 = pin[tid];            // prefetch u(t+2); hides under the MFMAs
    pin += 256;

    // A-fragments: 4 distinct addresses, broadcast over 16-lane groups.
    const h8* sp = (const h8*)sbuf[cur];
    h8 af[8];
#pragma unroll
    for (int c = 0; c < 8; ++c) af[c] = sp[4 * c + q];

    v4f a0 = {0.f, 0.f, 0.f, 0.f};
    v4f a1 = a0, a2 = a0, a3 = a0;
#pragma unroll
    for (int c = 0; c < 8; ++c) {
      a0 = __builtin_amdgcn_mfma_f32_16x16x32_f16(af[c], bw0[c], a0, 0, 0, 0);
      a1 = __builtin_amdgcn_mfma_f32_16x16x32_f16(af[c], bw1[c], a1, 0, 0, 0);
      a2 = __builtin_amdgcn_mfma_f32_16x16x32_f16(af[c], bw2[c], a2, 0, 0, 0);
      a3 = __builtin_amdgcn_mfma_f32_16x16x32_f16(af[c], bw3[c], a3, 0, 0, 0);
    }
    // lane's col = w*64 + 16q + r -> tile q, C row 4q -> acc elem 0
    float x = (q == 0) ? a0[0] : (q == 1) ? a1[0] : (q == 2) ? a2[0] : a3[0];
    x += u_cur + bst;

    // tanh(x) = 1 - 2/(exp2(2*log2e*x)+1)
    float e = exp2f(2.885390082f * x);
    float sn = 1.f - 2.f * __builtin_amdgcn_rcpf(e + 1.f);

    cur ^= 1;
    sbuf[cur][tid] = (_Float16)sn;    // ds_write_b16
    pst[tid] = (__bf16)sn;            // fire-and-forget global store
    pst += 256;
    u_cur = u_nxt;
    u_nxt = u_n2;
    BARRIER_LGKM();
  }
}

// ---------------------------------------------------------------- launch
extern "C" void kernel_launch(void* const* d_in, const int* in_sizes, int n_in,
                              void* d_out, int out_size, void* d_ws,
                              size_t ws_size, hipStream_t stream) {
  const float* x       = (const float*)d_in[0];  // [8,4096,1024]
  const float* W_in    = (const float*)d_in[1];  // [1024,256]
  const float* b_in    = (const float*)d_in[2];  // [256]
  const float* W_state = (const float*)d_in[3];  // [256,256]
  const float* b_state = (const float*)d_in[4];  // [256]
  const float* W_out   = (const float*)d_in[5];  // [256,1024]
  const float* b_out   = (const float*)d_in[6];  // [1024]
  float* out = (float*)d_out;                    // [8,4096,1024]

  const int B = 8, S = 4096, H = 1024, D = 256;
  const int M = B * S;  // 32768

  char* ws = (char*)d_ws;
  float*  inp    = (float*)(ws + 0);            // 32 MB  [M,D] f32
  __bf16* states = (__bf16*)(ws + 33554432);    // 16 MB  [M,D] bf16
  __bf16* xb     = (__bf16*)(ws + 50331648);    // 64 MB  [M,H] bf16
  __bf16* WinT   = (__bf16*)(ws + 117440512);   // 0.5 MB [D,H] bf16  (W_in^T)
  __bf16* WoutT  = (__bf16*)(ws + 117964800);   // 0.5 MB [H,D] bf16  (W_out^T)

  // conversions
  cvt_f32_bf16_x4<<<(M * H / 4 + 255) / 256, 256, 0, stream>>>(x, xb, M * H / 4);
  transpose_cvt<<<(H * D + 255) / 256, 256, 0, stream>>>(W_in, WinT, H, D);
  transpose_cvt<<<(D * H + 255) / 256, 256, 0, stream>>>(W_out, WoutT, D, H);

  // phase 1: inp = x @ W_in + b_in   (M=32768, N=256, K=1024) -> 512 blocks
  gemm_tile<<<(M / 128) * (D / 128), 256, 0, stream>>>(xb, WinT, b_in, inp, M, D, H);

  // phase 2: sequential scan, one block (4 waves) per batch
  scan_mfma<<<B, 256, 0, stream>>>(inp, W_state, b_state, states, S);

  // phase 3: out = states @ W_out + b_out  (M=32768, N=1024, K=256) -> 2048 blocks
  gemm_tile<<<(M / 128) * (H / 128), 256, 0, stream>>>(states, WoutT, b_out, out, M, H, D);
}

// Round 4
// 2112.829 us; speedup vs baseline: 1.3631x; 1.1616x over previous
//
#include <hip/hip_runtime.h>
#include <stdint.h>

// SSMTrack: B=8, S=4096, H=1024, D=256
//   inp = x @ W_in + b_in                    (tiled bf16 MFMA GEMM)
//   s_t = tanh(inp_t + s_{t-1} @ W_state + b_state)   (MFMA f16 scan, 1 WG/batch)
//   out = states @ W_out + b_out             (tiled bf16 MFMA GEMM)

typedef float v4f __attribute__((ext_vector_type(4)));
typedef __bf16 bf16x4 __attribute__((ext_vector_type(4)));
typedef __bf16 bf16x8 __attribute__((ext_vector_type(8)));
typedef _Float16 h8 __attribute__((ext_vector_type(8)));

#define BARRIER_LGKM() asm volatile("s_waitcnt lgkmcnt(0)\n\ts_barrier" ::: "memory")

#define GLOAD_LDS16(g, l)                                                    \
  __builtin_amdgcn_global_load_lds(                                          \
      (const __attribute__((address_space(1))) void*)(g),                    \
      (__attribute__((address_space(3))) void*)(l), 16, 0, 0)

// ---------------------------------------------------------------- conversions
__global__ void cvt_f32_bf16_x4(const float* __restrict__ in,
                                __bf16* __restrict__ out, int n4) {
  int i = blockIdx.x * blockDim.x + threadIdx.x;
  if (i >= n4) return;
  v4f v = ((const v4f*)in)[i];
  bf16x4 o;
  o.x = (__bf16)v.x; o.y = (__bf16)v.y; o.z = (__bf16)v.z; o.w = (__bf16)v.w;
  ((bf16x4*)out)[i] = o;
}

// in: [K,N] f32 row-major  ->  out: [N,K] bf16 row-major (i.e. B^T)
__global__ void transpose_cvt(const float* __restrict__ in,
                              __bf16* __restrict__ out, int K, int N) {
  int i = blockIdx.x * blockDim.x + threadIdx.x;
  if (i >= K * N) return;
  int k = i / N;
  int n = i - k * N;
  out[(size_t)n * K + k] = (__bf16)in[i];
}

// ---------------------------------------------------------------- GEMM (bf16)
// C[M,N](f32) = A[M,K](bf16 rm) * B + bias, with Bt[N,K] = B^T (bf16 rm).
// m97-style: 128x128 block tile, BK=32, 256 threads = 4 waves (2x2), each
// wave a 64x64 sub-tile = 4x4 fragments of 16x16x32 MFMA. Double-buffered
// LDS staged via global_load_lds (16B), one barrier per K-step.
// LDS swizzle: 16B-slot s of row -> s ^ ((row>>1)&3), applied by
// pre-swizzling the per-lane GLOBAL source slot (m173 pattern); ds_read
// applies the same XOR -> 2-way bank aliasing = free (m136).
__global__ __launch_bounds__(256) void gemm_tile(
    const __bf16* __restrict__ A,    // [M,K]
    const __bf16* __restrict__ Bt,   // [N,K]
    const float* __restrict__ bias,  // [N]
    float* __restrict__ C,           // [M,N]
    int M, int N, int K) {
  const int tid = threadIdx.x;
  const int lane = tid & 63;
  const int w = tid >> 6;          // wave 0..3
  const int wr = w >> 1, wc = w & 1;
  const int r = lane & 15, q = lane >> 4;

  const int nbn = N >> 7;
  const int mb = blockIdx.x / nbn;
  const int nb = blockIdx.x - mb * nbn;
  const int m0 = mb << 7, n0 = nb << 7;

  __shared__ __align__(16) char lds[2][16384];  // [buf][A 8K | B 8K]

  const __bf16* gA[2];
  const __bf16* gB[2];
  int loff[2];
#pragma unroll
  for (int j = 0; j < 2; ++j) {
    int o = (w * 2 + j) * 1024 + lane * 16;
    int row = o >> 6;
    int s = (o >> 4) & 3;
    int ss = s ^ ((row >> 1) & 3);  // source slot (inverse swizzle = same XOR)
    gA[j] = A + (size_t)(m0 + row) * K + ss * 8;
    gB[j] = Bt + (size_t)(n0 + row) * K + ss * 8;
    loff[j] = (w * 2 + j) * 1024;   // wave-uniform
  }

  const int slot = (q ^ ((r >> 1) & 3)) * 16;
  int aoff[4], boff[4];
#pragma unroll
  for (int i = 0; i < 4; ++i) {
    aoff[i] = (wr * 64 + i * 16 + r) * 64 + slot;
    boff[i] = 8192 + (wc * 64 + i * 16 + r) * 64 + slot;
  }

  v4f acc[4][4];
#pragma unroll
  for (int mi = 0; mi < 4; ++mi)
#pragma unroll
    for (int ni = 0; ni < 4; ++ni) acc[mi][ni] = (v4f){0.f, 0.f, 0.f, 0.f};

  const int NK = K >> 5;
#pragma unroll
  for (int j = 0; j < 2; ++j) {
    GLOAD_LDS16(gA[j], lds[0] + loff[j]);
    GLOAD_LDS16(gB[j], lds[0] + 8192 + loff[j]);
  }

  for (int kt = 0; kt < NK; ++kt) {
    __syncthreads();
    if (kt + 1 < NK) {
      const int b = (kt + 1) & 1;
      const int ke = (kt + 1) * 32;
#pragma unroll
      for (int j = 0; j < 2; ++j) {
        GLOAD_LDS16(gA[j] + ke, lds[b] + loff[j]);
        GLOAD_LDS16(gB[j] + ke, lds[b] + 8192 + loff[j]);
      }
    }
    const char* Lb = lds[kt & 1];
    bf16x8 af[4], bf[4];
#pragma unroll
    for (int i = 0; i < 4; ++i) af[i] = *(const bf16x8*)(Lb + aoff[i]);
#pragma unroll
    for (int i = 0; i < 4; ++i) bf[i] = *(const bf16x8*)(Lb + boff[i]);
#pragma unroll
    for (int mi = 0; mi < 4; ++mi)
#pragma unroll
      for (int ni = 0; ni < 4; ++ni)
        acc[mi][ni] = __builtin_amdgcn_mfma_f32_16x16x32_bf16(
            af[mi], bf[ni], acc[mi][ni], 0, 0, 0);
  }

  float bv[4];
#pragma unroll
  for (int ni = 0; ni < 4; ++ni) bv[ni] = bias[n0 + wc * 64 + ni * 16 + r];
#pragma unroll
  for (int mi = 0; mi < 4; ++mi) {
    int rowb = m0 + wr * 64 + mi * 16 + q * 4;
#pragma unroll
    for (int ni = 0; ni < 4; ++ni) {
      int col = n0 + wc * 64 + ni * 16 + r;
      float* cp = C + (size_t)rowb * N + col;
#pragma unroll
      for (int i = 0; i < 4; ++i) cp[(size_t)i * N] = acc[mi][ni][i] + bv[ni];
    }
  }
}

// ---------------------------------------------------------------- scan (MFMA)
// R3: 512 threads = 8 waves = 2 waves/SIMD. MFMA busy/step was invariant at
// ~507cy across R0-R2 while step was 1134-1269cy -> ~500cy of serial chain
// latency (ds_read ~120, depth-8 MFMA tail, tanh) was fully exposed at
// 1 wave/SIMD. Total MFMAs/block-step is fixed at 128 (weight panel /
// 16x32), so splitting into 8 waves x 16 MFMA keeps pipe time identical but
// lets the co-resident wave's MFMAs fill the other wave's latency bubbles.
// Wave w owns cols 32w..32w+31 (2 n-tiles); lanes q<2 are writers
// (col = 32w + 16q + r). All 16 A-rows alias the state vector (broadcast
// LDS read, addr depends on q only). W_state B-fragments: 64 VGPR/wave.
__global__ __launch_bounds__(512, 2) void scan_mfma(
    const float* __restrict__ inp,      // [B*S, 256] f32
    const float* __restrict__ Wst,      // [256, 256] f32
    const float* __restrict__ b_state,  // [256] f32
    __bf16* __restrict__ states,        // [B*S, 256] bf16 (out)
    int S) {
  const int tid = threadIdx.x;
  const int l = tid & 63;
  const int q = l >> 4;
  const int r = l & 15;
  const int w = tid >> 6;             // wave 0..7
  const int b = blockIdx.x;

  __shared__ __align__(16) _Float16 sbuf[2][256];

  // B-fragments for tiles 2w (bwA) and 2w+1 (bwB): lane holds B[k][col],
  // col = 32w + 16j + r, k = 32c + 8q + i.
  h8 bwA[8], bwB[8];
#pragma unroll
  for (int c = 0; c < 8; ++c) {
#pragma unroll
    for (int i = 0; i < 8; ++i) {
      const float* wp = Wst + (size_t)(32 * c + 8 * q + i) * 256 + 32 * w + r;
      bwA[c][i] = (_Float16)wp[0];
      bwB[c][i] = (_Float16)wp[16];
    }
  }

  const int col = 32 * w + 16 * (q & 1) + r;  // this lane's output column
  const float bst = b_state[col];
  const float* inpb = inp + (size_t)b * S * 256;
  __bf16* stb = states + (size_t)b * S * 256;

  if (tid < 256) sbuf[0][tid] = (_Float16)0.f;  // state0 = 0
  float u_cur = inpb[col];          // u for t=0
  float u_nxt = inpb[256 + col];    // u for t=1
  __syncthreads();

  int cur = 0;
  for (int t = 0; t < S; ++t) {
    // prefetch u(t+2); ~500cy global latency hides under 2 steps
    float u_n2 = 0.f;
    if (t + 2 < S) u_n2 = inpb[(size_t)(t + 2) * 256 + col];

    // A-fragments: addr = 64c + 16q bytes -> 4 distinct addresses,
    // broadcast over 16-lane groups; all 16 A-rows = state.
    const h8* sp = (const h8*)sbuf[cur];
    h8 af[8];
#pragma unroll
    for (int c = 0; c < 8; ++c) af[c] = sp[4 * c + q];

    v4f a0 = {0.f, 0.f, 0.f, 0.f};
    v4f a1 = a0;
#pragma unroll
    for (int c = 0; c < 8; ++c) {
      a0 = __builtin_amdgcn_mfma_f32_16x16x32_f16(af[c], bwA[c], a0, 0, 0, 0);
      a1 = __builtin_amdgcn_mfma_f32_16x16x32_f16(af[c], bwB[c], a1, 0, 0, 0);
    }
    // all C rows identical (A rows aliased) -> elem 0 of the right tile
    float x = ((q & 1) ? a1[0] : a0[0]) + u_cur + bst;

    // tanh(x) = 1 - 2/(exp2(2*log2e*x)+1)
    float e = exp2f(2.885390082f * x);
    float sn = 1.f - 2.f * __builtin_amdgcn_rcpf(e + 1.f);

    cur ^= 1;
    if (q < 2) {
      sbuf[cur][col] = (_Float16)sn;            // ds_write_b16
      stb[(size_t)t * 256 + col] = (__bf16)sn;  // fire-and-forget store
    }
    u_cur = u_nxt;
    u_nxt = u_n2;
    BARRIER_LGKM();
  }
}

// ---------------------------------------------------------------- launch
extern "C" void kernel_launch(void* const* d_in, const int* in_sizes, int n_in,
                              void* d_out, int out_size, void* d_ws,
                              size_t ws_size, hipStream_t stream) {
  const float* x       = (const float*)d_in[0];  // [8,4096,1024]
  const float* W_in    = (const float*)d_in[1];  // [1024,256]
  const float* b_in    = (const float*)d_in[2];  // [256]
  const float* W_state = (const float*)d_in[3];  // [256,256]
  const float* b_state = (const float*)d_in[4];  // [256]
  const float* W_out   = (const float*)d_in[5];  // [256,1024]
  const float* b_out   = (const float*)d_in[6];  // [1024]
  float* out = (float*)d_out;                    // [8,4096,1024]

  const int B = 8, S = 4096, H = 1024, D = 256;
  const int M = B * S;  // 32768

  char* ws = (char*)d_ws;
  float*  inp    = (float*)(ws + 0);            // 32 MB  [M,D] f32
  __bf16* states = (__bf16*)(ws + 33554432);    // 16 MB  [M,D] bf16
  __bf16* xb     = (__bf16*)(ws + 50331648);    // 64 MB  [M,H] bf16
  __bf16* WinT   = (__bf16*)(ws + 117440512);   // 0.5 MB [D,H] bf16  (W_in^T)
  __bf16* WoutT  = (__bf16*)(ws + 117964800);   // 0.5 MB [H,D] bf16  (W_out^T)

  // conversions
  cvt_f32_bf16_x4<<<(M * H / 4 + 255) / 256, 256, 0, stream>>>(x, xb, M * H / 4);
  transpose_cvt<<<(H * D + 255) / 256, 256, 0, stream>>>(W_in, WinT, H, D);
  transpose_cvt<<<(D * H + 255) / 256, 256, 0, stream>>>(W_out, WoutT, D, H);

  // phase 1: inp = x @ W_in + b_in   (M=32768, N=256, K=1024) -> 512 blocks
  gemm_tile<<<(M / 128) * (D / 128), 256, 0, stream>>>(xb, WinT, b_in, inp, M, D, H);

  // phase 2: sequential scan, one block (8 waves) per batch
  scan_mfma<<<B, 512, 0, stream>>>(inp, W_state, b_state, states, S);

  // phase 3: out = states @ W_out + b_out  (M=32768, N=1024, K=256) -> 2048 blocks
  gemm_tile<<<(M / 128) * (H / 128), 256, 0, stream>>>(states, WoutT, b_out, out, M, H, D);
}